// Round 10
// baseline (159.010 us; speedup 1.0000x reference)
//
#include <hip/hip_runtime.h>
#include <cstdint>
#include <cstddef>

// 20-qubit statevector sim, 3 layers of [U3 x20 + CU3 ring (0,1)..(19,0)].
// R10 = R3 body (best measured: 135.4us) + TWO full DUMMY passes appended
// after fin_k. R9's version crashed the container: it wrote dummy output
// at ws+24MB/ws+32MB, beyond the guaranteed workspace. Fixed: dummies
// recycle psiA/psiB (both DEAD after the final pass — each timed iteration
// re-creates psi from the INIT pass), and a <TYPE,0,0> pass never touches
// accum/out. Zero extra memory, zero correctness risk.
// Purpose: measure true marginal pass cost T_pass = (dur-135.4)/2 - 1.5us.
//   Theory A (harness floor): T_pass ~ 7us -> dur ~ 150-155.
//   Theory B (hidden in-pass cost): T_pass ~ 20us -> dur ~ 175-180.
//
// Pass internals (R3): NT=512, v[4], 4 waves/SIMD, 512 blocks, 11-bit
// tiles; window = bits (0,1); rotate-by-1 per phase, 10 phases, 9
// rotations (double-buffered, XOR-bank-swizzle SW(i)=i^((i>>3)&1));
// U3+CU3 fused per phase (W0, W1 = u_c*U3 precomputed in LDS).
//
// Pass S1(k): U3 q0..q10 + CU3 (0,1)..(9,10); tile bits 0..10 = q0..q10,
//   block bits = q11..q19.  Phase p (window = tile bits (p,p+1)):
//   p=0: U0 standalone + F(U1,C01); p>=1: F(U_{p+1}, C_{p,p+1}).
// Pass S2(k): tile = (q10,q11..q19,q0), block = q1..q9.
//   p=0..8: F(U_{11+p}, C_{10+p,11+p}); p=9: raw C(19,0) (U3 q0 done in S1).
// After 9 rotations: regs j=(tile bit9, bit10), t = tile bits 0..8.
// Inter-pass store (R0/R3-verified): f4 = b + t0*2^9 + (t>>1)*2^10 +
//   j0*2^18, content pairs over j1; reader loads contiguous 32B/thread.
// Final readout: R = j0 + 2*rev9(t) + 1024*rev9(b) + 2^19*j1 ->
//   float2 (x0,x1) at f2 idx rev9(t)+512*rev9(b), (x2,x3) at +2^18.
//   Block sum -> atomicAdd(accum); fin_k subtracts mean.

#define NB 512
#define NT 512
#define SW(i) ((i) ^ (((i) >> 3) & 1u))

__device__ __forceinline__ float2 cmadd2(float2 m0, float2 a0, float2 m1, float2 a1) {
  float2 r;
  r.x = m0.x * a0.x - m0.y * a0.y + m1.x * a1.x - m1.y * a1.y;
  r.y = m0.x * a0.y + m0.y * a0.x + m1.x * a1.y + m1.y * a1.x;
  return r;
}
__device__ __forceinline__ float2 cmul(float2 a, float2 b) {
  return make_float2(a.x * b.x - a.y * b.y, a.x * b.y + a.y * b.x);
}
__device__ __forceinline__ float2 cadd(float2 a, float2 b) {
  return make_float2(a.x + b.x, a.y + b.y);
}

// U3 on window bit0: pairs (0,1),(2,3)
__device__ __forceinline__ void applyU3b0(float2* v, const float2* m) {
  float2 m00 = m[0], m01 = m[1], m10 = m[2], m11 = m[3];
  float2 a0 = v[0], a1 = v[1];
  v[0] = cmadd2(m00, a0, m01, a1); v[1] = cmadd2(m10, a0, m11, a1);
  a0 = v[2]; a1 = v[3];
  v[2] = cmadd2(m00, a0, m01, a1); v[3] = cmadd2(m10, a0, m11, a1);
}
// fused [U3 on bit1, then CU3(ctrl=bit0,tgt=bit1)]: W0 acts on (v0,v2), W1 on (v1,v3)
__device__ __forceinline__ void applyF(float2* v, const float2* W0, const float2* W1) {
  float2 a0 = v[0], a1 = v[2];
  v[0] = cmadd2(W0[0], a0, W0[1], a1); v[2] = cmadd2(W0[2], a0, W0[3], a1);
  a0 = v[1]; a1 = v[3];
  v[1] = cmadd2(W1[0], a0, W1[1], a1); v[3] = cmadd2(W1[2], a0, W1[3], a1);
}
// raw CU3 ctrl bit0, tgt bit1: only (v1,v3)
__device__ __forceinline__ void applyC(float2* v, const float2* u) {
  float2 a0 = v[1], a1 = v[3];
  v[1] = cmadd2(u[0], a0, u[1], a1); v[3] = cmadd2(u[2], a0, u[3], a1);
}

__device__ __forceinline__ float xval(float2 a) {
  float p = a.x * a.x + a.y * a.y;
  return powf(0.8f * tanhf(52428.8f * p), 0.3f);
}

__device__ __forceinline__ void mat_from(const float* s, float2* m) {
  float st, ct, sl, cl, sp, cp, spl, cpl;
  sincosf(0.5f * s[0], &st, &ct);
  sincosf(s[2], &sl, &cl);
  sincosf(s[1], &sp, &cp);
  sincosf(s[1] + s[2], &spl, &cpl);
  m[0] = make_float2(ct, 0.f);
  m[1] = make_float2(-cl * st, -sl * st);
  m[2] = make_float2(cp * st, sp * st);
  m[3] = make_float2(cpl * ct, spl * ct);
}

// TYPE 0 = S1, 1 = S2; INIT synthesizes |0..0>; FINAL does readout.
template <int TYPE, int INIT, int FINAL>
__global__ __launch_bounds__(NT, 4) void pass_k(const float* __restrict__ u3p,
                                                const float* __restrict__ cu3p, int k,
                                                const float2* __restrict__ in,
                                                float2* __restrict__ outPsi,
                                                float* __restrict__ accum,
                                                float* __restrict__ out) {
  __shared__ float4 A4[1024], B4[1024];  // rotation double-buffer (16 KB each)
  __shared__ float2 M[168];              // MU: U3 q at [4q]; MC=M+80: W1 link c at [4c]
  __shared__ float red[8];
  unsigned t = threadIdx.x, b = blockIdx.x;

  // start psi loads first so they overlap the sincos below
  float2 v[4];
  if (INIT) {
    v[0] = v[1] = v[2] = v[3] = make_float2(0.f, 0.f);
    if (b == 0 && t == 0) { v[0] = make_float2(1.f, 0.f); *accum = 0.f; }
  } else {
    const float4* in4 = (const float4*)in + ((size_t)b << 10) + 2u * t;
    float4 f0 = in4[0], f1 = in4[1];
    v[0] = make_float2(f0.x, f0.y); v[1] = make_float2(f0.z, f0.w);
    v[2] = make_float2(f1.x, f1.y); v[3] = make_float2(f1.z, f1.w);
  }

  // this layer's matrices: MU[q] = U3(q); MC[c] = u_c * U3(c+1) (fused W1),
  // except MC[19] = raw u_19 (its target q0's U3 was already applied in S1).
  float2* MU = M;
  float2* MC = M + 80;
  if (t < 20) {
    mat_from(u3p + (k * 20 + t) * 3, MU + 4 * t);
  } else if (t >= 64 && t < 84) {
    unsigned c = t - 64;
    float2 u[4];
    mat_from(cu3p + (k * 20 + c) * 3, u);
    if (c == 19) {
      MC[76] = u[0]; MC[77] = u[1]; MC[78] = u[2]; MC[79] = u[3];
    } else {
      float2 ut[4];
      mat_from(u3p + (k * 20 + c + 1) * 3, ut);
      MC[4 * c + 0] = cadd(cmul(u[0], ut[0]), cmul(u[1], ut[2]));
      MC[4 * c + 1] = cadd(cmul(u[0], ut[1]), cmul(u[1], ut[3]));
      MC[4 * c + 2] = cadd(cmul(u[2], ut[0]), cmul(u[3], ut[2]));
      MC[4 * c + 3] = cadd(cmul(u[2], ut[1]), cmul(u[3], ut[3]));
    }
  }
  __syncthreads();

  // 10 phases; window = tile bits (p, p+1); rotate-by-1 between phases.
#pragma unroll
  for (int p = 0; p < 10; ++p) {
    if (TYPE == 0) {
      if (p == 0) applyU3b0(v, MU);             // U0 standalone
      applyF(v, MU + 4 * (p + 1), MC + 4 * p);  // U_{p+1} + C_{p,p+1}
    } else {
      if (p < 9) applyF(v, MU + 4 * (11 + p), MC + 4 * (10 + p));
      else       applyC(v, MC + 4 * 19);        // raw C(19,0)
    }
    if (p < 9) {
      // rotate-by-1: L' = (L>>1)|((L&1)<<10). Thread regs L=4t+j:
      // f4[t]=(v0,v2) [f2 2t,2t+1]; f4[t+512]=(v1,v3) [f2 2t+1024,+1025]
      float4* buf = (p & 1) ? B4 : A4;
      buf[SW(t)]        = make_float4(v[0].x, v[0].y, v[2].x, v[2].y);
      buf[SW(t + 512u)] = make_float4(v[1].x, v[1].y, v[3].x, v[3].y);
      __syncthreads();
      float4 fa = buf[SW(2u * t)], fb = buf[SW(2u * t + 1u)];
      v[0] = make_float2(fa.x, fa.y); v[1] = make_float2(fa.z, fa.w);
      v[2] = make_float2(fb.x, fb.y); v[3] = make_float2(fb.z, fb.w);
    }
  }

  // final regs: j=(tile bit9, bit10), t = tile bits 0..8.
  if (!FINAL) {
    // inter-pass layout: f4 = b + t0*2^9 + (t>>1)*2^10 + j0*2^18, pair over j1.
    float4* o4 = (float4*)outPsi;
    unsigned base = b + ((t & 1u) << 9) + ((t >> 1) << 10);
    o4[base]              = make_float4(v[0].x, v[0].y, v[2].x, v[2].y);
    o4[base + (1u << 18)] = make_float4(v[1].x, v[1].y, v[3].x, v[3].y);
  } else {
    // S2(2) end: j0=q19, j1=q0, t=(q10..q18), b=(q1..q9).
    // R = j0 + 2*rev9(t) + 1024*rev9(b) + 2^19*j1
    float xv0 = xval(v[0]), xv1 = xval(v[1]), xv2 = xval(v[2]), xv3 = xval(v[3]);
    float s = xv0 + xv1 + xv2 + xv3;
    float2* o2 = (float2*)out;
    unsigned rt = __brev(t) >> 23, rb = __brev(b) >> 23;
    unsigned base = rt + (rb << 9);
    o2[base] = make_float2(xv0, xv1);
    o2[base + (1u << 18)] = make_float2(xv2, xv3);
#pragma unroll
    for (int o = 32; o > 0; o >>= 1) s += __shfl_down(s, o);
    if ((t & 63u) == 0) red[t >> 6] = s;
    __syncthreads();
    if (t == 0) {
      float tot = 0.f;
#pragma unroll
      for (int i = 0; i < 8; i++) tot += red[i];
      atomicAdd(accum, tot);
    }
  }
}

__global__ void fin_k(float* __restrict__ out, const float* __restrict__ accum) {
  unsigned i = blockIdx.x * blockDim.x + threadIdx.x;
  float mean = *accum * (1.f / 1048576.f);
  float4* o4 = (float4*)out;
  float4 x = o4[i];
  x.x -= mean; x.y -= mean; x.z -= mean; x.w -= mean;
  o4[i] = x;
}

extern "C" void kernel_launch(void* const* d_in, const int* in_sizes, int n_in,
                              void* d_out, int out_size, void* d_ws, size_t ws_size,
                              hipStream_t stream) {
  const float* u3p = (const float*)d_in[0];
  const float* cu3p = (const float*)d_in[1];
  float* out = (float*)d_out;

  char* ws = (char*)d_ws;
  float2* psiA = (float2*)ws;                              // 8 MB
  float2* psiB = (float2*)(ws + (size_t)8 * 1024 * 1024);  // 8 MB
  float* accum = (float*)(ws + (size_t)16 * 1024 * 1024);

  pass_k<0, 1, 0><<<NB, NT, 0, stream>>>(u3p, cu3p, 0, nullptr, psiB, accum, out);
  pass_k<1, 0, 0><<<NB, NT, 0, stream>>>(u3p, cu3p, 0, psiB, psiA, accum, out);
  pass_k<0, 0, 0><<<NB, NT, 0, stream>>>(u3p, cu3p, 1, psiA, psiB, accum, out);
  pass_k<1, 0, 0><<<NB, NT, 0, stream>>>(u3p, cu3p, 1, psiB, psiA, accum, out);
  pass_k<0, 0, 0><<<NB, NT, 0, stream>>>(u3p, cu3p, 2, psiA, psiB, accum, out);
  pass_k<1, 0, 1><<<NB, NT, 0, stream>>>(u3p, cu3p, 2, psiB, nullptr, accum, out);
  fin_k<<<1024, 256, 0, stream>>>(out, accum);
  // --- T_pass probes: two full dummy passes recycling dead psiA/psiB.
  // <TYPE,0,0> passes never touch accum or out; each timed iteration
  // rebuilds psi from the INIT pass, so clobbering psiA/psiB here is safe.
  pass_k<0, 0, 0><<<NB, NT, 0, stream>>>(u3p, cu3p, 0, psiB, psiA, accum, out);
  pass_k<1, 0, 0><<<NB, NT, 0, stream>>>(u3p, cu3p, 0, psiA, psiB, accum, out);
}

// Round 11
// 127.521 us; speedup vs baseline: 1.2469x; 1.2469x over previous
//
#include <hip/hip_runtime.h>
#include <cstdint>
#include <cstddef>

// 20-qubit statevector sim, 3 layers of [U3 x20 + CU3 ring (0,1)..(19,0)].
// R11: 6 dispatches — merged INIT+S1(0)+S2(0) kernel, then 4 tile passes,
// then fin_k. R10 probe: T_pass = 10.3us, boundaries 1.5us -> controllable
// time ~75us of the 135 (rest = harness poison fills in the timed window).
// Pass-count is the remaining lever. After S1(0), psi is nonzero ONLY at
// q11..q19 = 0 (one 2^11 tile): every S2(0) block recomputes the 11-qubit
// S1(0) state in LDS (same cost as one pass body, NO global I/O) and
// synthesizes its 4 nonzero input amps directly:
//   S2 block b'=(q1..q9); nonzero inputs at t' in {0,256} (q0=t'>>8),
//   j' in {0,1} (q10=j'): psi1_idx = (t'>>8) + (b'<<1) + (j'<<10).
// psi1 stash: S1-end regs j=(q9,q10), t=(q0..q8) -> lds1[t + 512*j].
// Saves one dispatch + 16MB global traffic vs R3's separate passes.
//
// Pass internals (R3, verified): NT=512, v[4], 4 waves/SIMD, 512 blocks,
// 11-bit tiles; window = bits (0,1); rotate-by-1 per phase, 10 phases, 9
// rotations (double-buffered, XOR-bank-swizzle SW(i)=i^((i>>3)&1));
// U3+CU3 fused per phase (W0, W1 = u_c*U3 precomputed in LDS).
// S1(k): U3 q0..q10 + CU3 (0,1)..(9,10); S2(k): U3 q11..q19 + CU3
// (10,11)..(19,0), tile=(q10,...,q19,q0), block=(q1..q9).
// Inter-pass store (verified): f4 = b + t0*2^9 + (t>>1)*2^10 + j0*2^18,
// content pairs over j1; reader loads contiguous 32B/thread.
// Final readout: R = j0 + 2*rev9(t) + 1024*rev9(b) + 2^19*j1; block sum
// -> atomicAdd(accum); fin_k subtracts mean.

#define NB 512
#define NT 512
#define SW(i) ((i) ^ (((i) >> 3) & 1u))

__device__ __forceinline__ float2 cmadd2(float2 m0, float2 a0, float2 m1, float2 a1) {
  float2 r;
  r.x = m0.x * a0.x - m0.y * a0.y + m1.x * a1.x - m1.y * a1.y;
  r.y = m0.x * a0.y + m0.y * a0.x + m1.x * a1.y + m1.y * a1.x;
  return r;
}
__device__ __forceinline__ float2 cmul(float2 a, float2 b) {
  return make_float2(a.x * b.x - a.y * b.y, a.x * b.y + a.y * b.x);
}
__device__ __forceinline__ float2 cadd(float2 a, float2 b) {
  return make_float2(a.x + b.x, a.y + b.y);
}

// U3 on window bit0: pairs (0,1),(2,3)
__device__ __forceinline__ void applyU3b0(float2* v, const float2* m) {
  float2 m00 = m[0], m01 = m[1], m10 = m[2], m11 = m[3];
  float2 a0 = v[0], a1 = v[1];
  v[0] = cmadd2(m00, a0, m01, a1); v[1] = cmadd2(m10, a0, m11, a1);
  a0 = v[2]; a1 = v[3];
  v[2] = cmadd2(m00, a0, m01, a1); v[3] = cmadd2(m10, a0, m11, a1);
}
// fused [U3 on bit1, then CU3(ctrl=bit0,tgt=bit1)]: W0 acts on (v0,v2), W1 on (v1,v3)
__device__ __forceinline__ void applyF(float2* v, const float2* W0, const float2* W1) {
  float2 a0 = v[0], a1 = v[2];
  v[0] = cmadd2(W0[0], a0, W0[1], a1); v[2] = cmadd2(W0[2], a0, W0[3], a1);
  a0 = v[1]; a1 = v[3];
  v[1] = cmadd2(W1[0], a0, W1[1], a1); v[3] = cmadd2(W1[2], a0, W1[3], a1);
}
// raw CU3 ctrl bit0, tgt bit1: only (v1,v3)
__device__ __forceinline__ void applyC(float2* v, const float2* u) {
  float2 a0 = v[1], a1 = v[3];
  v[1] = cmadd2(u[0], a0, u[1], a1); v[3] = cmadd2(u[2], a0, u[3], a1);
}

__device__ __forceinline__ float xval(float2 a) {
  float p = a.x * a.x + a.y * a.y;
  return powf(0.8f * tanhf(52428.8f * p), 0.3f);
}

__device__ __forceinline__ void mat_from(const float* s, float2* m) {
  float st, ct, sl, cl, sp, cp, spl, cpl;
  sincosf(0.5f * s[0], &st, &ct);
  sincosf(s[2], &sl, &cl);
  sincosf(s[1], &sp, &cp);
  sincosf(s[1] + s[2], &spl, &cpl);
  m[0] = make_float2(ct, 0.f);
  m[1] = make_float2(-cl * st, -sl * st);
  m[2] = make_float2(cp * st, sp * st);
  m[3] = make_float2(cpl * ct, spl * ct);
}

// shared matrix stage: MU[q]=U3(q); MC[c]=u_c*U3(c+1) fused, MC[19]=raw u19.
__device__ __forceinline__ void load_mats(const float* u3p, const float* cu3p,
                                          int k, unsigned t, float2* MU, float2* MC) {
  if (t < 20) {
    mat_from(u3p + (k * 20 + t) * 3, MU + 4 * t);
  } else if (t >= 64 && t < 84) {
    unsigned c = t - 64;
    float2 u[4];
    mat_from(cu3p + (k * 20 + c) * 3, u);
    if (c == 19) {
      MC[76] = u[0]; MC[77] = u[1]; MC[78] = u[2]; MC[79] = u[3];
    } else {
      float2 ut[4];
      mat_from(u3p + (k * 20 + c + 1) * 3, ut);
      MC[4 * c + 0] = cadd(cmul(u[0], ut[0]), cmul(u[1], ut[2]));
      MC[4 * c + 1] = cadd(cmul(u[0], ut[1]), cmul(u[1], ut[3]));
      MC[4 * c + 2] = cadd(cmul(u[2], ut[0]), cmul(u[3], ut[2]));
      MC[4 * c + 3] = cadd(cmul(u[2], ut[1]), cmul(u[3], ut[3]));
    }
  }
}

// TYPE 0 = S1, 1 = S2; FINAL does readout.
template <int TYPE, int FINAL>
__global__ __launch_bounds__(NT, 4) void pass_k(const float* __restrict__ u3p,
                                                const float* __restrict__ cu3p, int k,
                                                const float2* __restrict__ in,
                                                float2* __restrict__ outPsi,
                                                float* __restrict__ accum,
                                                float* __restrict__ out) {
  __shared__ float4 A4[1024], B4[1024];  // rotation double-buffer (16 KB each)
  __shared__ float2 M[168];
  __shared__ float red[8];
  unsigned t = threadIdx.x, b = blockIdx.x;

  float2 v[4];
  {
    const float4* in4 = (const float4*)in + ((size_t)b << 10) + 2u * t;
    float4 f0 = in4[0], f1 = in4[1];
    v[0] = make_float2(f0.x, f0.y); v[1] = make_float2(f0.z, f0.w);
    v[2] = make_float2(f1.x, f1.y); v[3] = make_float2(f1.z, f1.w);
  }
  float2* MU = M;
  float2* MC = M + 80;
  load_mats(u3p, cu3p, k, t, MU, MC);
  __syncthreads();

#pragma unroll
  for (int p = 0; p < 10; ++p) {
    if (TYPE == 0) {
      if (p == 0) applyU3b0(v, MU);
      applyF(v, MU + 4 * (p + 1), MC + 4 * p);
    } else {
      if (p < 9) applyF(v, MU + 4 * (11 + p), MC + 4 * (10 + p));
      else       applyC(v, MC + 4 * 19);
    }
    if (p < 9) {
      float4* buf = (p & 1) ? B4 : A4;
      buf[SW(t)]        = make_float4(v[0].x, v[0].y, v[2].x, v[2].y);
      buf[SW(t + 512u)] = make_float4(v[1].x, v[1].y, v[3].x, v[3].y);
      __syncthreads();
      float4 fa = buf[SW(2u * t)], fb = buf[SW(2u * t + 1u)];
      v[0] = make_float2(fa.x, fa.y); v[1] = make_float2(fa.z, fa.w);
      v[2] = make_float2(fb.x, fb.y); v[3] = make_float2(fb.z, fb.w);
    }
  }

  if (!FINAL) {
    float4* o4 = (float4*)outPsi;
    unsigned base = b + ((t & 1u) << 9) + ((t >> 1) << 10);
    o4[base]              = make_float4(v[0].x, v[0].y, v[2].x, v[2].y);
    o4[base + (1u << 18)] = make_float4(v[1].x, v[1].y, v[3].x, v[3].y);
  } else {
    float xv0 = xval(v[0]), xv1 = xval(v[1]), xv2 = xval(v[2]), xv3 = xval(v[3]);
    float s = xv0 + xv1 + xv2 + xv3;
    float2* o2 = (float2*)out;
    unsigned rt = __brev(t) >> 23, rb = __brev(b) >> 23;
    unsigned base = rt + (rb << 9);
    o2[base] = make_float2(xv0, xv1);
    o2[base + (1u << 18)] = make_float2(xv2, xv3);
#pragma unroll
    for (int o = 32; o > 0; o >>= 1) s += __shfl_down(s, o);
    if ((t & 63u) == 0) red[t >> 6] = s;
    __syncthreads();
    if (t == 0) {
      float tot = 0.f;
#pragma unroll
      for (int i = 0; i < 8; i++) tot += red[i];
      atomicAdd(accum, tot);
    }
  }
}

// Merged INIT + S1(0) (in-LDS, every block replicates the 2^11-amp sim)
// + handoff + S2(0). Writes outPsi in the standard inter-pass layout.
__global__ __launch_bounds__(NT, 4) void init2_k(const float* __restrict__ u3p,
                                                 const float* __restrict__ cu3p,
                                                 float2* __restrict__ outPsi,
                                                 float* __restrict__ accum) {
  __shared__ float4 A4[1024], B4[1024];
  __shared__ float2 M[168];
  unsigned t = threadIdx.x, b = blockIdx.x;

  float2 v[4];
  v[0] = v[1] = v[2] = v[3] = make_float2(0.f, 0.f);
  if (t == 0) v[0] = make_float2(1.f, 0.f);   // every block: |0..0> of the 11-qubit sim
  if (b == 0 && t == 0) *accum = 0.f;

  float2* MU = M;
  float2* MC = M + 80;
  load_mats(u3p, cu3p, 0, t, MU, MC);
  __syncthreads();

  // ---- S1(0) body, entirely in LDS/regs ----
#pragma unroll
  for (int p = 0; p < 10; ++p) {
    if (p == 0) applyU3b0(v, MU);
    applyF(v, MU + 4 * (p + 1), MC + 4 * p);
    if (p < 9) {
      float4* buf = (p & 1) ? B4 : A4;
      buf[SW(t)]        = make_float4(v[0].x, v[0].y, v[2].x, v[2].y);
      buf[SW(t + 512u)] = make_float4(v[1].x, v[1].y, v[3].x, v[3].y);
      __syncthreads();
      float4 fa = buf[SW(2u * t)], fb = buf[SW(2u * t + 1u)];
      v[0] = make_float2(fa.x, fa.y); v[1] = make_float2(fa.z, fa.w);
      v[2] = make_float2(fb.x, fb.y); v[3] = make_float2(fb.z, fb.w);
    }
  }
  // S1 end: regs j=(q9,q10), t=(q0..q8). Stash psi1 into B4 (free: last
  // rotation used A4): psi1_idx = t + 512*j  (bit9=q9, bit10=q10).
  float2* lds1 = (float2*)B4;
  lds1[t]         = v[0];
  lds1[t + 512u]  = v[1];
  lds1[t + 1024u] = v[2];
  lds1[t + 1536u] = v[3];
  __syncthreads();

  // ---- handoff: S2 block b=(q1..q9); nonzero inputs need q11..q19=0 ->
  // t in {0,256} (q0=t>>8), regs j in {0,1} (q10=j):
  // psi1_idx = (t>>8) + (b<<1) + (j<<10).
  v[0] = v[1] = v[2] = v[3] = make_float2(0.f, 0.f);
  if ((t & 255u) == 0) {
    unsigned idx = (t >> 8) + (b << 1);
    v[0] = lds1[idx];
    v[1] = lds1[idx + 1024u];
  }
  // no barrier needed before first rotation write (targets A4, not B4);
  // B4 is first overwritten at rotation p=1, after p=0's barrier.

  // ---- S2(0) body ----
#pragma unroll
  for (int p = 0; p < 10; ++p) {
    if (p < 9) applyF(v, MU + 4 * (11 + p), MC + 4 * (10 + p));
    else       applyC(v, MC + 4 * 19);
    if (p < 9) {
      float4* buf = (p & 1) ? B4 : A4;
      buf[SW(t)]        = make_float4(v[0].x, v[0].y, v[2].x, v[2].y);
      buf[SW(t + 512u)] = make_float4(v[1].x, v[1].y, v[3].x, v[3].y);
      __syncthreads();
      float4 fa = buf[SW(2u * t)], fb = buf[SW(2u * t + 1u)];
      v[0] = make_float2(fa.x, fa.y); v[1] = make_float2(fa.z, fa.w);
      v[2] = make_float2(fb.x, fb.y); v[3] = make_float2(fb.z, fb.w);
    }
  }

  float4* o4 = (float4*)outPsi;
  unsigned base = b + ((t & 1u) << 9) + ((t >> 1) << 10);
  o4[base]              = make_float4(v[0].x, v[0].y, v[2].x, v[2].y);
  o4[base + (1u << 18)] = make_float4(v[1].x, v[1].y, v[3].x, v[3].y);
}

__global__ void fin_k(float* __restrict__ out, const float* __restrict__ accum) {
  unsigned i = blockIdx.x * blockDim.x + threadIdx.x;
  float mean = *accum * (1.f / 1048576.f);
  float4* o4 = (float4*)out;
  float4 x = o4[i];
  x.x -= mean; x.y -= mean; x.z -= mean; x.w -= mean;
  o4[i] = x;
}

extern "C" void kernel_launch(void* const* d_in, const int* in_sizes, int n_in,
                              void* d_out, int out_size, void* d_ws, size_t ws_size,
                              hipStream_t stream) {
  const float* u3p = (const float*)d_in[0];
  const float* cu3p = (const float*)d_in[1];
  float* out = (float*)d_out;

  char* ws = (char*)d_ws;
  float2* psiA = (float2*)ws;                              // 8 MB
  float2* psiB = (float2*)(ws + (size_t)8 * 1024 * 1024);  // 8 MB
  float* accum = (float*)(ws + (size_t)16 * 1024 * 1024);

  init2_k<<<NB, NT, 0, stream>>>(u3p, cu3p, psiA, accum);            // L0 (S1+S2 fused)
  pass_k<0, 0><<<NB, NT, 0, stream>>>(u3p, cu3p, 1, psiA, psiB, accum, out);  // S1(1)
  pass_k<1, 0><<<NB, NT, 0, stream>>>(u3p, cu3p, 1, psiB, psiA, accum, out);  // S2(1)
  pass_k<0, 0><<<NB, NT, 0, stream>>>(u3p, cu3p, 2, psiA, psiB, accum, out);  // S1(2)
  pass_k<1, 1><<<NB, NT, 0, stream>>>(u3p, cu3p, 2, psiB, nullptr, accum, out); // S2(2)+readout
  fin_k<<<1024, 256, 0, stream>>>(out, accum);
}